// Round 2
// baseline (187.929 us; speedup 1.0000x reference)
//
#include <hip/hip_runtime.h>

#define N_PIX 8192
#define C_DIM 128
#define TAU_INV_LOG2E 20.609929155556622f  // log2(e) / 0.07
#define EPS_DEN 1e-8f
#define NT_TILES 68                        // 4 classes each padded to x128: <= 8192 + 4*127 -> 68 tiles
#define NT_ROWS (NT_TILES * 128)           // 8704
#define FAKE_ROWS (NT_ROWS - N_PIX)        // 512 zero rows, each contributes exp2(0)=1 to den

typedef unsigned short u16;
typedef __attribute__((ext_vector_type(8))) short short8;
typedef __attribute__((ext_vector_type(4))) float f32x4;

__device__ __forceinline__ u16 f2bf(float f) {
    unsigned u = __float_as_uint(f);
    return (u16)((u + 0x7fffu + ((u >> 16) & 1u)) >> 16);  // RNE
}

// meta layout (ints): [0..3] cls_counter (scatter ranks), [4..8] padded_start[5],
//                     [12..15] pad_count[4], [16..16+NT_TILES) tile_class
// ---------------- Kernel 1: class histogram + padded layout + tile classes ----------------
__global__ __launch_bounds__(256) void hist_k(const int* __restrict__ tseg,
                                              int* __restrict__ meta) {
    __shared__ int hcnt[4][4];
    int t = threadIdx.x;
    int c0 = 0, c1 = 0, c2 = 0, c3 = 0;
    for (int i = t; i < N_PIX; i += 256) {
        int v = tseg[i];
        c0 += (v == 0); c1 += (v == 1); c2 += (v == 2); c3 += (v == 3);
    }
#pragma unroll
    for (int off = 32; off; off >>= 1) {
        c0 += __shfl_down(c0, off); c1 += __shfl_down(c1, off);
        c2 += __shfl_down(c2, off); c3 += __shfl_down(c3, off);
    }
    int wave = t >> 6;
    if ((t & 63) == 0) { hcnt[wave][0] = c0; hcnt[wave][1] = c1; hcnt[wave][2] = c2; hcnt[wave][3] = c3; }
    __syncthreads();
    if (t == 0) {
        int ps[5]; ps[0] = 0;
#pragma unroll
        for (int c = 0; c < 4; ++c) {
            int cnt = hcnt[0][c] + hcnt[1][c] + hcnt[2][c] + hcnt[3][c];
            int padded = (cnt + 127) & ~127;
            ps[c + 1] = ps[c] + padded;
            meta[12 + c] = padded - cnt;   // pad_count
            meta[c] = 0;                   // cls_counter
        }
#pragma unroll
        for (int c = 0; c < 5; ++c) meta[4 + c] = ps[c];
        for (int tt = 0; tt < NT_TILES; ++tt) {
            int row = tt * 128, cl = 4;
#pragma unroll
            for (int c = 0; c < 4; ++c)
                if (row >= ps[c] && row < ps[c + 1]) cl = c;
            meta[16 + tt] = cl;
        }
    }
}

// ------ Kernel 2: fused L2-normalize + transpose (+ tau-scale & class-scatter for target) ------
__global__ __launch_bounds__(256) void norm_write_k(const float* __restrict__ input,
                                                    const float* __restrict__ target,
                                                    const int* __restrict__ tseg,
                                                    int* __restrict__ meta,
                                                    u16* __restrict__ ni_bf,
                                                    u16* __restrict__ nt_sorted) {
    __shared__ float tile[128][65];
    __shared__ float sscale[64];
    __shared__ int sdest[64];
    int arr = blockIdx.z;            // 0 = input, 1 = target
    int bb = blockIdx.y;
    int hw0 = blockIdx.x * 64;
    const float* src = (arr ? target : input) + bb * (C_DIM * 4096);
    int t = threadIdx.x;
    int tq = t >> 6, tl = t & 63;
#pragma unroll
    for (int i = 0; i < 32; ++i) {
        int c = i * 4 + tq;
        tile[c][tl] = src[c * 4096 + hw0 + tl];   // coalesced along hw
    }
    __syncthreads();
    // 4 threads per pixel sum-of-squares
    int p = t >> 2, sub = t & 3;
    float ss = 0.f;
#pragma unroll
    for (int i = 0; i < 32; ++i) {
        float v = tile[sub * 32 + i][p];
        ss += v * v;
    }
    ss += __shfl_xor(ss, 1);
    ss += __shfl_xor(ss, 2);
    if (sub == 0) {
        float sc = 1.0f / fmaxf(sqrtf(ss), 1e-12f);
        int n = bb * 4096 + hw0 + p;
        int dest;
        if (arr) {
            sc *= TAU_INV_LOG2E;                   // fold tau into target rows
            int c = tseg[n];
            int rank = atomicAdd(&meta[c], 1);     // order within class irrelevant
            dest = meta[4 + c] + rank;
        } else {
            dest = n;
        }
        sscale[p] = sc;
        sdest[p] = dest;
    }
    __syncthreads();
    u16* dst = arr ? nt_sorted : ni_bf;
#pragma unroll
    for (int i = 0; i < 4; ++i) {
        int idx = t + i * 256;
        int px = idx >> 4, kc = idx & 15;
        float sc = sscale[px];
        long drow = sdest[px];
        short8 o;
#pragma unroll
        for (int j = 0; j < 8; ++j)
            o[j] = (short)f2bf(tile[kc * 8 + j][px] * sc);
        *(short8*)(dst + drow * C_DIM + kc * 8) = o;   // 16B stores
    }
}

// ---------------- Kernel 3: fused GEMM + exp + class-uniform-tile column sums ----------------
__global__ __launch_bounds__(256, 2) void main_k(const u16* __restrict__ ni,
                                                 const u16* __restrict__ nt,
                                                 const int* __restrict__ piseg,
                                                 const int* __restrict__ meta,
                                                 float* __restrict__ den,
                                                 float* __restrict__ nom) {
    __shared__ __align__(16) u16 sA[128 * 136];   // A-tile, padded stride 136 bf16

    int bcb = blockIdx.x & 63;     // 128-column block of b (input pixels)
    int as  = blockIdx.x >> 6;     // a-split index (0..7)
    int t0  = as * 8 + (as < 4 ? as : 4);       // tiles: 9,9,9,9,8,8,8,8 (= 68)
    int ntl = 8 + (as < 4 ? 1 : 0);
    int bcol0 = bcb * 128;
    int tid = threadIdx.x;
    int lane = tid & 63;
    int wave = tid >> 6;
    int wr = wave >> 1, wc = wave & 1;   // 2x2 waves over 128x128 tile
    int l15 = lane & 15, q = lane >> 4;
    const int* tcls = meta + 16;

    // B fragments: loop-invariant, held in registers (L2-resident source)
    short8 bfrag[4][4];
    int pil[4];
#pragma unroll
    for (int ct = 0; ct < 4; ++ct) {
        int brow = bcol0 + wc * 64 + ct * 16 + l15;
        pil[ct] = piseg[brow];
        const u16* bp = ni + brow * C_DIM + q * 8;
#pragma unroll
        for (int kc = 0; kc < 4; ++kc)
            bfrag[ct][kc] = *(const short8*)(bp + kc * 32);
    }

    float den_l[4] = {0.f, 0.f, 0.f, 0.f};
    float nom_l[4] = {0.f, 0.f, 0.f, 0.f};

    for (int it = 0; it < ntl; ++it) {
        int tile = t0 + it;
        int a0 = tile * 128;
        __syncthreads();   // previous iteration's sA reads done
        {
            const uint4* gsrc = (const uint4*)(nt + (long)a0 * C_DIM);  // 2048 x 16B contiguous
#pragma unroll
            for (int i = 0; i < 8; ++i) {
                int idx = tid + i * 256;
                int r = idx >> 4, ch = idx & 15;
                *(uint4*)(&sA[r * 136 + ch * 8]) = gsrc[idx];
            }
        }
        __syncthreads();

        f32x4 acc[4][4] = {};
#pragma unroll
        for (int kc = 0; kc < 4; ++kc) {
            short8 af[4];
#pragma unroll
            for (int rt = 0; rt < 4; ++rt) {
                int ar = wr * 64 + rt * 16 + l15;
                af[rt] = *(const short8*)(&sA[ar * 136 + kc * 32 + q * 8]);
            }
#pragma unroll
            for (int rt = 0; rt < 4; ++rt)
#pragma unroll
                for (int ct = 0; ct < 4; ++ct)
                    acc[rt][ct] = __builtin_amdgcn_mfma_f32_16x16x32_bf16(
                        af[rt], bfrag[ct][kc], acc[rt][ct], 0, 0, 0);
        }

        // epilogue: e = exp2(sim_scaled); whole tile has one class -> one compare per ct
        int tc = tcls[tile];
        float td[4] = {0.f, 0.f, 0.f, 0.f};
#pragma unroll
        for (int rt = 0; rt < 4; ++rt)
#pragma unroll
            for (int ct = 0; ct < 4; ++ct) {
                f32x4 v = acc[rt][ct];
                float e0 = __builtin_amdgcn_exp2f(v[0]);
                float e1 = __builtin_amdgcn_exp2f(v[1]);
                float e2 = __builtin_amdgcn_exp2f(v[2]);
                float e3 = __builtin_amdgcn_exp2f(v[3]);
                td[ct] += (e0 + e1) + (e2 + e3);
            }
#pragma unroll
        for (int ct = 0; ct < 4; ++ct) {
            den_l[ct] += td[ct];
            nom_l[ct] += (tc == pil[ct]) ? td[ct] : 0.f;
        }
    }

    // reduce across the 4 quads (same column, different rows), then atomics
#pragma unroll
    for (int ct = 0; ct < 4; ++ct) {
        float d = den_l[ct], nm = nom_l[ct];
        d += __shfl_xor(d, 16); d += __shfl_xor(d, 32);
        nm += __shfl_xor(nm, 16); nm += __shfl_xor(nm, 32);
        if (lane < 16) {
            int b = bcol0 + wc * 64 + ct * 16 + lane;
            atomicAdd(&den[b], d);
            atomicAdd(&nom[b], nm);
        }
    }
}

// ---------------- Kernel 4: loss = mean(-log(nom/(den+eps))) with pad corrections ----------------
__global__ __launch_bounds__(256) void loss_k(const float* __restrict__ den,
                                              const float* __restrict__ nom,
                                              const int* __restrict__ piseg,
                                              const int* __restrict__ meta,
                                              float* __restrict__ out) {
    const int* padc = meta + 12;
    float s = 0.f;
    for (int i = threadIdx.x; i < N_PIX; i += 256) {
        float nm = nom[i] - (float)padc[piseg[i]];
        float d = den[i] - (float)FAKE_ROWS;
        s -= __logf(nm / (d + EPS_DEN));
    }
#pragma unroll
    for (int off = 32; off > 0; off >>= 1) s += __shfl_down(s, off);
    __shared__ float part[4];
    int wave = threadIdx.x >> 6;
    if ((threadIdx.x & 63) == 0) part[wave] = s;
    __syncthreads();
    if (threadIdx.x == 0)
        out[0] = (part[0] + part[1] + part[2] + part[3]) * (1.0f / N_PIX);
}

extern "C" void kernel_launch(void* const* d_in, const int* in_sizes, int n_in,
                              void* d_out, int out_size, void* d_ws, size_t ws_size,
                              hipStream_t stream) {
    const float* input  = (const float*)d_in[0];
    const float* target = (const float*)d_in[1];
    const int*   iseg   = (const int*)d_in[2];
    const int*   tseg   = (const int*)d_in[3];
    float* out = (float*)d_out;

    char* ws = (char*)d_ws;
    u16* ni_bf     = (u16*)(ws);                    // 8192*128 bf16 = 2 MB
    u16* nt_sorted = (u16*)(ws + 0x200000);         // 8704*128 bf16 = 0x220000
    float* den     = (float*)(ws + 0x420000);       // 32 KB
    float* nom     = (float*)(ws + 0x428000);       // 32 KB
    int* meta      = (int*)(ws + 0x430000);         // counters / offsets / tile classes

    // zero nt_sorted (pad rows must be zero vectors) + den + nom in one contiguous memset
    hipMemsetAsync(ws + 0x200000, 0, 0x230000, stream);
    hist_k<<<1, 256, 0, stream>>>(tseg, meta);
    norm_write_k<<<dim3(64, 2, 2), 256, 0, stream>>>(input, target, tseg, meta, ni_bf, nt_sorted);
    main_k<<<512, 256, 0, stream>>>(ni_bf, nt_sorted, iseg, meta, den, nom);
    loss_k<<<1, 256, 0, stream>>>(den, nom, iseg, meta, out);
}

// Round 3
// 114.139 us; speedup vs baseline: 1.6465x; 1.6465x over previous
//
#include <hip/hip_runtime.h>

#define N_PIX 8192
#define C_DIM 128
#define TAU_INV_LOG2E 20.609929155556622f  // log2(e) / 0.07
#define EPS_DEN 1e-8f
#define NT_TILES 68                        // 4 classes each padded to x128: <= 8192 + 4*127 -> 68 tiles
#define NT_ROWS (NT_TILES * 128)           // 8704
#define FAKE_ROWS (NT_ROWS - N_PIX)        // 512 zero rows, each contributes exp2(0)=1 to den

typedef unsigned short u16;
typedef __attribute__((ext_vector_type(8))) short short8;
typedef __attribute__((ext_vector_type(4))) float f32x4;

__device__ __forceinline__ u16 f2bf(float f) {
    unsigned u = __float_as_uint(f);
    return (u16)((u + 0x7fffu + ((u >> 16) & 1u)) >> 16);  // RNE
}

// meta layout (ints): [12..15] pad_count[4], [16..16+NT_TILES) tile_class
// ---------- Kernel 1: counting-sort ranks (atomic-free) + padded layout + tile classes ----------
__global__ __launch_bounds__(256) void hist_k(const int* __restrict__ tseg,
                                              int* __restrict__ meta,
                                              int* __restrict__ dest) {
    int t = threadIdx.x;
    int lane = t & 63, w = t >> 6;
    int base = t * 32;
    // per-thread class counts over a contiguous 32-pixel chunk
    int c0 = 0, c1 = 0, c2 = 0, c3 = 0;
#pragma unroll
    for (int i = 0; i < 32; ++i) {
        int v = tseg[base + i];
        c0 += (v == 0); c1 += (v == 1); c2 += (v == 2); c3 += (v == 3);
    }
    int cnt[4] = {c0, c1, c2, c3};
    int excl[4], wtot[4];
#pragma unroll
    for (int c = 0; c < 4; ++c) {
        int s = cnt[c];
#pragma unroll
        for (int off = 1; off < 64; off <<= 1) {
            int y = __shfl_up(s, off);
            if (lane >= off) s += y;
        }
        excl[c] = s - cnt[c];          // exclusive prefix within wave
        wtot[c] = __shfl(s, 63);       // wave total
    }
    __shared__ int wt[4][4];
    if (lane == 63) {
        wt[w][0] = wtot[0]; wt[w][1] = wtot[1]; wt[w][2] = wtot[2]; wt[w][3] = wtot[3];
    }
    __syncthreads();
    int ps[5]; ps[0] = 0;
    int wbase[4];
#pragma unroll
    for (int c = 0; c < 4; ++c) {
        int t0 = wt[0][c], t1 = wt[1][c], t2 = wt[2][c], t3 = wt[3][c];
        int tot = t0 + t1 + t2 + t3;
        wbase[c] = (w > 0 ? t0 : 0) + (w > 1 ? t1 : 0) + (w > 2 ? t2 : 0);
        int padded = (tot + 127) & ~127;
        ps[c + 1] = ps[c] + padded;
        if (t == 0) meta[12 + c] = padded - tot;   // pad_count
    }
    int tb0 = ps[0] + wbase[0] + excl[0];
    int tb1 = ps[1] + wbase[1] + excl[1];
    int tb2 = ps[2] + wbase[2] + excl[2];
    int tb3 = ps[3] + wbase[3] + excl[3];
#pragma unroll
    for (int i = 0; i < 32; ++i) {
        int v = tseg[base + i];
        int d = (v == 0) ? tb0 : (v == 1) ? tb1 : (v == 2) ? tb2 : tb3;
        tb0 += (v == 0); tb1 += (v == 1); tb2 += (v == 2); tb3 += (v == 3);
        dest[base + i] = d;
    }
    if (t < NT_TILES) {
        int row = t * 128, cl = 4;
#pragma unroll
        for (int c = 0; c < 4; ++c)
            if (row >= ps[c] && row < ps[c + 1]) cl = c;
        meta[16 + t] = cl;
    }
}

// ------ Kernel 2: fused L2-normalize + transpose (+ tau-scale & class-scatter for target) ------
__global__ __launch_bounds__(256) void norm_write_k(const float* __restrict__ input,
                                                    const float* __restrict__ target,
                                                    const int* __restrict__ dest,
                                                    u16* __restrict__ ni_bf,
                                                    u16* __restrict__ nt_sorted) {
    __shared__ float tile[128][65];
    __shared__ float sscale[64];
    __shared__ int sdest[64];
    int arr = blockIdx.z;            // 0 = input, 1 = target
    int bb = blockIdx.y;
    int hw0 = blockIdx.x * 64;
    const float* src = (arr ? target : input) + bb * (C_DIM * 4096);
    int t = threadIdx.x;
    int tq = t >> 6, tl = t & 63;
#pragma unroll
    for (int i = 0; i < 32; ++i) {
        int c = i * 4 + tq;
        tile[c][tl] = src[c * 4096 + hw0 + tl];   // coalesced along hw
    }
    __syncthreads();
    // 4 threads per pixel sum-of-squares
    int p = t >> 2, sub = t & 3;
    float ss = 0.f;
#pragma unroll
    for (int i = 0; i < 32; ++i) {
        float v = tile[sub * 32 + i][p];
        ss += v * v;
    }
    ss += __shfl_xor(ss, 1);
    ss += __shfl_xor(ss, 2);
    if (sub == 0) {
        float sc = 1.0f / fmaxf(sqrtf(ss), 1e-12f);
        int n = bb * 4096 + hw0 + p;
        int dst_row;
        if (arr) {
            sc *= TAU_INV_LOG2E;                   // fold tau into target rows
            dst_row = dest[n];                     // precomputed rank (no atomics)
        } else {
            dst_row = n;
        }
        sscale[p] = sc;
        sdest[p] = dst_row;
    }
    __syncthreads();
    u16* dst = arr ? nt_sorted : ni_bf;
#pragma unroll
    for (int i = 0; i < 4; ++i) {
        int idx = t + i * 256;
        int px = idx >> 4, kc = idx & 15;
        float sc = sscale[px];
        long drow = sdest[px];
        short8 o;
#pragma unroll
        for (int j = 0; j < 8; ++j)
            o[j] = (short)f2bf(tile[kc * 8 + j][px] * sc);
        *(short8*)(dst + drow * C_DIM + kc * 8) = o;   // 16B stores
    }
}

// ---------------- Kernel 3: fused GEMM + exp + class-uniform-tile column sums ----------------
__global__ __launch_bounds__(256, 2) void main_k(const u16* __restrict__ ni,
                                                 const u16* __restrict__ nt,
                                                 const int* __restrict__ piseg,
                                                 const int* __restrict__ meta,
                                                 float* __restrict__ den,
                                                 float* __restrict__ nom) {
    __shared__ __align__(16) u16 sA[128 * 136];   // A-tile, padded stride 136 bf16

    int bcb = blockIdx.x & 63;     // 128-column block of b (input pixels)
    int as  = blockIdx.x >> 6;     // a-split index (0..7)
    int t0  = as * 8 + (as < 4 ? as : 4);       // tiles: 9,9,9,9,8,8,8,8 (= 68)
    int ntl = 8 + (as < 4 ? 1 : 0);
    int bcol0 = bcb * 128;
    int tid = threadIdx.x;
    int lane = tid & 63;
    int wave = tid >> 6;
    int wr = wave >> 1, wc = wave & 1;   // 2x2 waves over 128x128 tile
    int l15 = lane & 15, q = lane >> 4;
    const int* tcls = meta + 16;

    // B fragments: loop-invariant, held in registers (L2-resident source)
    short8 bfrag[4][4];
    int pil[4];
#pragma unroll
    for (int ct = 0; ct < 4; ++ct) {
        int brow = bcol0 + wc * 64 + ct * 16 + l15;
        pil[ct] = piseg[brow];
        const u16* bp = ni + brow * C_DIM + q * 8;
#pragma unroll
        for (int kc = 0; kc < 4; ++kc)
            bfrag[ct][kc] = *(const short8*)(bp + kc * 32);
    }

    float den_l[4] = {0.f, 0.f, 0.f, 0.f};
    float nom_l[4] = {0.f, 0.f, 0.f, 0.f};

    for (int it = 0; it < ntl; ++it) {
        int tile = t0 + it;
        int a0 = tile * 128;
        __syncthreads();   // previous iteration's sA reads done
        {
            const uint4* gsrc = (const uint4*)(nt + (long)a0 * C_DIM);  // 2048 x 16B contiguous
#pragma unroll
            for (int i = 0; i < 8; ++i) {
                int idx = tid + i * 256;
                int r = idx >> 4, ch = idx & 15;
                *(uint4*)(&sA[r * 136 + ch * 8]) = gsrc[idx];
            }
        }
        __syncthreads();

        f32x4 acc[4][4] = {};
#pragma unroll
        for (int kc = 0; kc < 4; ++kc) {
            short8 af[4];
#pragma unroll
            for (int rt = 0; rt < 4; ++rt) {
                int ar = wr * 64 + rt * 16 + l15;
                af[rt] = *(const short8*)(&sA[ar * 136 + kc * 32 + q * 8]);
            }
#pragma unroll
            for (int rt = 0; rt < 4; ++rt)
#pragma unroll
                for (int ct = 0; ct < 4; ++ct)
                    acc[rt][ct] = __builtin_amdgcn_mfma_f32_16x16x32_bf16(
                        af[rt], bfrag[ct][kc], acc[rt][ct], 0, 0, 0);
        }

        // epilogue: e = exp2(sim_scaled); whole tile has one class -> one compare per ct
        int tc = tcls[tile];
        float td[4] = {0.f, 0.f, 0.f, 0.f};
#pragma unroll
        for (int rt = 0; rt < 4; ++rt)
#pragma unroll
            for (int ct = 0; ct < 4; ++ct) {
                f32x4 v = acc[rt][ct];
                float e0 = __builtin_amdgcn_exp2f(v[0]);
                float e1 = __builtin_amdgcn_exp2f(v[1]);
                float e2 = __builtin_amdgcn_exp2f(v[2]);
                float e3 = __builtin_amdgcn_exp2f(v[3]);
                td[ct] += (e0 + e1) + (e2 + e3);
            }
#pragma unroll
        for (int ct = 0; ct < 4; ++ct) {
            den_l[ct] += td[ct];
            nom_l[ct] += (tc == pil[ct]) ? td[ct] : 0.f;
        }
    }

    // reduce across the 4 quads (same column, different rows), then atomics
#pragma unroll
    for (int ct = 0; ct < 4; ++ct) {
        float d = den_l[ct], nm = nom_l[ct];
        d += __shfl_xor(d, 16); d += __shfl_xor(d, 32);
        nm += __shfl_xor(nm, 16); nm += __shfl_xor(nm, 32);
        if (lane < 16) {
            int b = bcol0 + wc * 64 + ct * 16 + lane;
            atomicAdd(&den[b], d);
            atomicAdd(&nom[b], nm);
        }
    }
}

// ---------------- Kernel 4: loss = mean(-log(nom/(den+eps))) with pad corrections ----------------
__global__ __launch_bounds__(256) void loss_k(const float* __restrict__ den,
                                              const float* __restrict__ nom,
                                              const int* __restrict__ piseg,
                                              const int* __restrict__ meta,
                                              float* __restrict__ out) {
    const int* padc = meta + 12;
    float s = 0.f;
    for (int i = threadIdx.x; i < N_PIX; i += 256) {
        float nm = nom[i] - (float)padc[piseg[i]];
        float d = den[i] - (float)FAKE_ROWS;
        s -= __logf(nm / (d + EPS_DEN));
    }
#pragma unroll
    for (int off = 32; off > 0; off >>= 1) s += __shfl_down(s, off);
    __shared__ float part[4];
    int wave = threadIdx.x >> 6;
    if ((threadIdx.x & 63) == 0) part[wave] = s;
    __syncthreads();
    if (threadIdx.x == 0)
        out[0] = (part[0] + part[1] + part[2] + part[3]) * (1.0f / N_PIX);
}

extern "C" void kernel_launch(void* const* d_in, const int* in_sizes, int n_in,
                              void* d_out, int out_size, void* d_ws, size_t ws_size,
                              hipStream_t stream) {
    const float* input  = (const float*)d_in[0];
    const float* target = (const float*)d_in[1];
    const int*   iseg   = (const int*)d_in[2];
    const int*   tseg   = (const int*)d_in[3];
    float* out = (float*)d_out;

    char* ws = (char*)d_ws;
    u16* ni_bf     = (u16*)(ws);                    // 8192*128 bf16 = 2 MB
    u16* nt_sorted = (u16*)(ws + 0x200000);         // 8704*128 bf16 = 0x220000
    float* den     = (float*)(ws + 0x420000);       // 32 KB
    float* nom     = (float*)(ws + 0x428000);       // 32 KB
    int* meta      = (int*)(ws + 0x430000);         // pad counts / tile classes
    int* dest      = (int*)(ws + 0x440000);         // 8192 ints: scatter permutation

    // zero nt_sorted (pad rows must be zero vectors) + den + nom in one contiguous memset
    hipMemsetAsync(ws + 0x200000, 0, 0x230000, stream);
    hist_k<<<1, 256, 0, stream>>>(tseg, meta, dest);
    norm_write_k<<<dim3(64, 2, 2), 256, 0, stream>>>(input, target, dest, ni_bf, nt_sorted);
    main_k<<<512, 256, 0, stream>>>(ni_bf, nt_sorted, iseg, meta, den, nom);
    loss_k<<<1, 256, 0, stream>>>(den, nom, iseg, meta, out);
}

// Round 4
// 94.464 us; speedup vs baseline: 1.9894x; 1.2083x over previous
//
#include <hip/hip_runtime.h>

#define N_PIX 8192
#define C_DIM 128
#define TAU_INV_LOG2E 20.609929155556622f  // log2(e) / 0.07
#define EPS_DEN 1e-8f
#define NT_TILES 68                        // 4 classes each padded to x128 + tail -> 68 tiles
#define NT_ROWS (NT_TILES * 128)           // 8704
#define FAKE_ROWS (NT_ROWS - N_PIX)        // exactly 512 zero rows; each adds exp2(0)=1 to den

typedef unsigned short u16;
typedef __attribute__((ext_vector_type(8))) short short8;
typedef __attribute__((ext_vector_type(4))) float f32x4;

__device__ __forceinline__ u16 f2bf(float f) {
    unsigned u = __float_as_uint(f);
    return (u16)((u + 0x7fffu + ((u >> 16) & 1u)) >> 16);  // RNE
}

// meta layout (ints): [12..15] pad_count[4], [16..16+NT_TILES) tile_class
// ---- Kernel 1: fused L2-normalize + transpose + (target) inline counting-sort scatter ----
// grid (64, 2, 2): z=0 input (row-major dest), z=1 target (class-sorted dest, tau folded).
// Also: input blocks zero den/nom; target blocks zero the 512 pad/tail rows; block (0,0,1)
// writes meta. All consumed only by LATER kernels (kernel-boundary coherence).
__global__ __launch_bounds__(256) void norm_write_k(const float* __restrict__ input,
                                                    const float* __restrict__ target,
                                                    const int* __restrict__ tseg,
                                                    int* __restrict__ meta,
                                                    u16* __restrict__ ni_bf,
                                                    u16* __restrict__ nt_sorted,
                                                    float* __restrict__ den,
                                                    float* __restrict__ nom) {
    __shared__ float tile[128][65];
    __shared__ float sscale[64];
    __shared__ int sdest[64];
    __shared__ int chunkcnt[256][4];   // per-32-pixel-chunk class counts
    __shared__ int pfx[256][4];        // exclusive prefix per chunk per class
    __shared__ int tot[4];

    int arr = blockIdx.z;            // 0 = input, 1 = target
    int bb = blockIdx.y;
    int hw0 = blockIdx.x * 64;
    int bi = bb * 64 + blockIdx.x;   // 0..127 within this z-slice
    const float* src = (arr ? target : input) + bb * (C_DIM * 4096);
    int t = threadIdx.x;
    int lane = t & 63, w = t >> 6;
    int tq = w, tl = lane;

    if (arr == 0) {
        // zero den/nom (8192 floats each, 64 per block)
        if (t < 64) den[bi * 64 + t] = 0.f;
        else if (t < 128) nom[bi * 64 + (t - 64)] = 0.f;
    }

    // ---- load 128x64 fp32 tile (coalesced along hw) ----
#pragma unroll
    for (int i = 0; i < 32; ++i) {
        int c = i * 4 + tq;
        tile[c][tl] = src[c * 4096 + hw0 + tl];
    }

    int ps[5];
    int padc[4];
    if (arr) {
        // ---- redundant per-block histogram of full tseg (32 KB, L2-hot) ----
        int v[8][4];  // not stored; accumulate counts
        int c0 = 0, c1 = 0, c2 = 0, c3 = 0;
        const int4* ts4 = (const int4*)tseg;
#pragma unroll
        for (int j = 0; j < 8; ++j) {
            int4 x = ts4[t * 8 + j];
            c0 += (x.x == 0) + (x.y == 0) + (x.z == 0) + (x.w == 0);
            c1 += (x.x == 1) + (x.y == 1) + (x.z == 1) + (x.w == 1);
            c2 += (x.x == 2) + (x.y == 2) + (x.z == 2) + (x.w == 2);
            c3 += (x.x == 3) + (x.y == 3) + (x.z == 3) + (x.w == 3);
        }
        (void)v;
        chunkcnt[t][0] = c0; chunkcnt[t][1] = c1; chunkcnt[t][2] = c2; chunkcnt[t][3] = c3;
    }
    __syncthreads();

    if (arr) {
        // ---- scan: wave w handles class w across 256 chunks ----
        int c = w;
        int vv[4];
#pragma unroll
        for (int j = 0; j < 4; ++j) vv[j] = chunkcnt[lane * 4 + j][c];
        int s = vv[0] + vv[1] + vv[2] + vv[3];
        int si = s;
#pragma unroll
        for (int off = 1; off < 64; off <<= 1) {
            int y = __shfl_up(si, off);
            if (lane >= off) si += y;
        }
        int run = si - s;
#pragma unroll
        for (int j = 0; j < 4; ++j) { pfx[lane * 4 + j][c] = run; run += vv[j]; }
        if (lane == 63) tot[c] = si;
    }
    __syncthreads();

    if (arr) {
        ps[0] = 0;
#pragma unroll
        for (int c = 0; c < 4; ++c) {
            int tc = tot[c];
            int padded = (tc + 127) & ~127;
            ps[c + 1] = ps[c] + padded;
            padc[c] = padded - tc;
        }
        // designated block writes meta
        if (blockIdx.x == 0 && bb == 0) {
            if (t < 4) meta[12 + t] = padc[t];
            if (t < NT_TILES) {
                int row = t * 128, cl = 4;
#pragma unroll
                for (int c = 0; c < 4; ++c)
                    if (row >= ps[c] && row < ps[c + 1]) cl = c;
                meta[16 + t] = cl;
            }
        }
        // zero the 512 pad/tail rows: 4 rows per block, 16B stores by 64 threads
        if (t < 64) {
            int g = bi + (t >> 4) * 128;     // global zero-row index 0..511
            int gg = g, c;
            for (c = 0; c < 4; ++c) { if (gg < padc[c]) break; gg -= padc[c]; }
            int row = (c < 4) ? (ps[c + 1] - padc[c] + gg) : (ps[4] + gg);
            short8 z = {};
            *(short8*)(nt_sorted + (long)row * C_DIM + (t & 15) * 8) = z;
        }
    }

    // ---- per-pixel sum of squares (4 threads per pixel) ----
    int p = t >> 2, sub = t & 3;
    float ss = 0.f;
#pragma unroll
    for (int i = 0; i < 32; ++i) {
        float vv = tile[sub * 32 + i][p];
        ss += vv * vv;
    }
    ss += __shfl_xor(ss, 1);
    ss += __shfl_xor(ss, 2);
    if (sub == 0) {
        float sc = 1.0f / fmaxf(sqrtf(ss), 1e-12f);
        int n = bb * 4096 + hw0 + p;
        int dst_row;
        if (arr) {
            sc *= TAU_INV_LOG2E;             // fold tau into target rows
            int c = tseg[n];
            int chunk = n >> 5, pos = n & 31;
            int r = 0;
            for (int j = 0; j < pos; ++j) r += (tseg[chunk * 32 + j] == c);
            dst_row = ps[c] + pfx[chunk][c] + r;
        } else {
            dst_row = n;
        }
        sscale[p] = sc;
        sdest[p] = dst_row;
    }
    __syncthreads();

    u16* dst = arr ? nt_sorted : ni_bf;
#pragma unroll
    for (int i = 0; i < 4; ++i) {
        int idx = t + i * 256;
        int px = idx >> 4, kc = idx & 15;
        float sc = sscale[px];
        long drow = sdest[px];
        short8 o;
#pragma unroll
        for (int j = 0; j < 8; ++j)
            o[j] = (short)f2bf(tile[kc * 8 + j][px] * sc);
        *(short8*)(dst + drow * C_DIM + kc * 8) = o;   // 16B stores
    }
}

// ---------------- Kernel 2: fused GEMM + exp + class-uniform-tile column sums ----------------
__global__ __launch_bounds__(256, 2) void main_k(const u16* __restrict__ ni,
                                                 const u16* __restrict__ nt,
                                                 const int* __restrict__ piseg,
                                                 const int* __restrict__ meta,
                                                 float* __restrict__ den,
                                                 float* __restrict__ nom) {
    __shared__ __align__(16) u16 sA[128 * 136];   // A-tile, padded stride 136 bf16

    int bcb = blockIdx.x & 63;     // 128-column block of b (input pixels)
    int as  = blockIdx.x >> 6;     // a-split index (0..7)
    int t0  = as * 8 + (as < 4 ? as : 4);       // tiles: 9,9,9,9,8,8,8,8 (= 68)
    int ntl = 8 + (as < 4 ? 1 : 0);
    int bcol0 = bcb * 128;
    int tid = threadIdx.x;
    int lane = tid & 63;
    int wave = tid >> 6;
    int wr = wave >> 1, wc = wave & 1;   // 2x2 waves over 128x128 tile
    int l15 = lane & 15, q = lane >> 4;
    const int* tcls = meta + 16;

    // B fragments: loop-invariant, held in registers (L2-resident source)
    short8 bfrag[4][4];
    int pil[4];
#pragma unroll
    for (int ct = 0; ct < 4; ++ct) {
        int brow = bcol0 + wc * 64 + ct * 16 + l15;
        pil[ct] = piseg[brow];
        const u16* bp = ni + brow * C_DIM + q * 8;
#pragma unroll
        for (int kc = 0; kc < 4; ++kc)
            bfrag[ct][kc] = *(const short8*)(bp + kc * 32);
    }

    float den_l[4] = {0.f, 0.f, 0.f, 0.f};
    float nom_l[4] = {0.f, 0.f, 0.f, 0.f};

    for (int it = 0; it < ntl; ++it) {
        int tile = t0 + it;
        int a0 = tile * 128;
        __syncthreads();   // previous iteration's sA reads done
        {
            const uint4* gsrc = (const uint4*)(nt + (long)a0 * C_DIM);  // 2048 x 16B contiguous
#pragma unroll
            for (int i = 0; i < 8; ++i) {
                int idx = tid + i * 256;
                int r = idx >> 4, ch = idx & 15;
                *(uint4*)(&sA[r * 136 + ch * 8]) = gsrc[idx];
            }
        }
        __syncthreads();

        f32x4 acc[4][4] = {};
#pragma unroll
        for (int kc = 0; kc < 4; ++kc) {
            short8 af[4];
#pragma unroll
            for (int rt = 0; rt < 4; ++rt) {
                int ar = wr * 64 + rt * 16 + l15;
                af[rt] = *(const short8*)(&sA[ar * 136 + kc * 32 + q * 8]);
            }
#pragma unroll
            for (int rt = 0; rt < 4; ++rt)
#pragma unroll
                for (int ct = 0; ct < 4; ++ct)
                    acc[rt][ct] = __builtin_amdgcn_mfma_f32_16x16x32_bf16(
                        af[rt], bfrag[ct][kc], acc[rt][ct], 0, 0, 0);
        }

        // epilogue: e = exp2(sim_scaled); whole tile has one class -> one compare per ct
        int tc = tcls[tile];
        float td[4] = {0.f, 0.f, 0.f, 0.f};
#pragma unroll
        for (int rt = 0; rt < 4; ++rt)
#pragma unroll
            for (int ct = 0; ct < 4; ++ct) {
                f32x4 v = acc[rt][ct];
                float e0 = __builtin_amdgcn_exp2f(v[0]);
                float e1 = __builtin_amdgcn_exp2f(v[1]);
                float e2 = __builtin_amdgcn_exp2f(v[2]);
                float e3 = __builtin_amdgcn_exp2f(v[3]);
                td[ct] += (e0 + e1) + (e2 + e3);
            }
#pragma unroll
        for (int ct = 0; ct < 4; ++ct) {
            den_l[ct] += td[ct];
            nom_l[ct] += (tc == pil[ct]) ? td[ct] : 0.f;
        }
    }

    // reduce across the 4 quads (same column, different rows), then atomics
#pragma unroll
    for (int ct = 0; ct < 4; ++ct) {
        float d = den_l[ct], nm = nom_l[ct];
        d += __shfl_xor(d, 16); d += __shfl_xor(d, 32);
        nm += __shfl_xor(nm, 16); nm += __shfl_xor(nm, 32);
        if (lane < 16) {
            int b = bcol0 + wc * 64 + ct * 16 + lane;
            atomicAdd(&den[b], d);
            atomicAdd(&nom[b], nm);
        }
    }
}

// ---------------- Kernel 3: loss = mean(-log(nom/(den+eps))) with pad corrections ----------------
__global__ __launch_bounds__(1024) void loss_k(const float* __restrict__ den,
                                               const float* __restrict__ nom,
                                               const int* __restrict__ piseg,
                                               const int* __restrict__ meta,
                                               float* __restrict__ out) {
    int t = threadIdx.x;
    float padcf[4];
#pragma unroll
    for (int c = 0; c < 4; ++c) padcf[c] = (float)meta[12 + c];
    int base = t * 8;
    float s = 0.f;
#pragma unroll
    for (int h = 0; h < 2; ++h) {
        float4 d4 = *(const float4*)(den + base + h * 4);
        float4 n4 = *(const float4*)(nom + base + h * 4);
        int4  p4 = *(const int4*)(piseg + base + h * 4);
        float dd[4] = {d4.x, d4.y, d4.z, d4.w};
        float nn[4] = {n4.x, n4.y, n4.z, n4.w};
        int   pp[4] = {p4.x, p4.y, p4.z, p4.w};
#pragma unroll
        for (int j = 0; j < 4; ++j) {
            float nm = nn[j] - padcf[pp[j]];
            float d = dd[j] - (float)FAKE_ROWS;
            s -= __logf(nm / (d + EPS_DEN));
        }
    }
#pragma unroll
    for (int off = 32; off > 0; off >>= 1) s += __shfl_down(s, off);
    __shared__ float part[16];
    int wave = t >> 6;
    if ((t & 63) == 0) part[wave] = s;
    __syncthreads();
    if (t == 0) {
        float acc = 0.f;
#pragma unroll
        for (int i = 0; i < 16; ++i) acc += part[i];
        out[0] = acc * (1.0f / N_PIX);
    }
}

extern "C" void kernel_launch(void* const* d_in, const int* in_sizes, int n_in,
                              void* d_out, int out_size, void* d_ws, size_t ws_size,
                              hipStream_t stream) {
    const float* input  = (const float*)d_in[0];
    const float* target = (const float*)d_in[1];
    const int*   iseg   = (const int*)d_in[2];
    const int*   tseg   = (const int*)d_in[3];
    float* out = (float*)d_out;

    char* ws = (char*)d_ws;
    u16* ni_bf     = (u16*)(ws);                    // 8192*128 bf16 = 2 MB
    u16* nt_sorted = (u16*)(ws + 0x200000);         // 8704*128 bf16
    float* den     = (float*)(ws + 0x420000);       // 32 KB
    float* nom     = (float*)(ws + 0x428000);       // 32 KB
    int* meta      = (int*)(ws + 0x430000);         // pad counts / tile classes

    norm_write_k<<<dim3(64, 2, 2), 256, 0, stream>>>(input, target, tseg, meta,
                                                     ni_bf, nt_sorted, den, nom);
    main_k<<<512, 256, 0, stream>>>(ni_bf, nt_sorted, iseg, meta, den, nom);
    loss_k<<<1, 1024, 0, stream>>>(den, nom, iseg, meta, out);
}